// Round 1
// baseline (331.865 us; speedup 1.0000x reference)
//
#include <hip/hip_runtime.h>

// Cross-correlation: out[ch, o] = sum_t d1[ch, t + o - 301] * d2[ch, t]
//   ch in [0, 2048), o in [0, 603), t in [0, 3000), zero-padded d1.
//
// Block = 2 channels, 320 threads. LDS stages padded d1 (3604 f32/ch) and d2
// (3008 f32/ch). Each active thread (302 of 320) computes 4 consecutive lags
// with a rolling float4 window: 16 fp32 FMAs per 2 ds_read_b128.

#define NT      3000
#define NOUT    603
#define PAD     301
#define L1LEN   3604        // indices 0..3603 used; 16B-aligned row
#define L2LEN   3008
#define GROUPS  151         // lag-groups of 4 -> covers lags 0..603
#define CHPB    2
#define ACTIVE  (CHPB * GROUPS)   // 302
#define BLOCK   320

__global__ __launch_bounds__(BLOCK) void xcorr_fp32_kernel(
    const float* __restrict__ d1g, const float* __restrict__ d2g,
    float* __restrict__ out)
{
    __shared__ __align__(16) float ld1[CHPB][L1LEN];
    __shared__ __align__(16) float ld2[CHPB][L2LEN];

    const int tid    = threadIdx.x;
    const int chBase = blockIdx.x * CHPB;

    // Zero only the pad regions of ld1 (disjoint from the fill region below,
    // so no barrier needed between the two loops).
    for (int i = tid; i < L1LEN; i += BLOCK) {
        if (i < PAD || i >= PAD + NT) { ld1[0][i] = 0.f; ld1[1][i] = 0.f; }
    }

    // Stage both channels: vectorized global float4 loads.
    const float* g1 = d1g + (size_t)chBase * NT;
    const float* g2 = d2g + (size_t)chBase * NT;
    for (int idx = tid; idx < CHPB * (NT / 4); idx += BLOCK) {
        const int c = idx / (NT / 4);
        const int j = (idx % (NT / 4)) * 4;
        const float4 v = *(const float4*)(g1 + c * NT + j);
        ld1[c][PAD + j + 0] = v.x;
        ld1[c][PAD + j + 1] = v.y;
        ld1[c][PAD + j + 2] = v.z;
        ld1[c][PAD + j + 3] = v.w;
        const float4 w = *(const float4*)(g2 + c * NT + j);
        *(float4*)&ld2[c][j] = w;
    }
    __syncthreads();

    if (tid >= ACTIVE) return;   // no further barriers -> early return is safe

    const int c    = tid / GROUPS;
    const int g    = tid % GROUPS;
    const int base = 4 * g;                       // first lag of this thread
    const float* __restrict__ A = ld1[c];
    const float* __restrict__ B = ld2[c];

    float a0 = 0.f, a1 = 0.f, a2 = 0.f, a3 = 0.f;
    float4 w0 = *(const float4*)(A + base);       // window [base .. base+3]

    #pragma unroll 2
    for (int t = 0; t < NT; t += 4) {
        const float4 w1 = *(const float4*)(A + base + t + 4);  // next 4
        const float4 y  = *(const float4*)(B + t);             // broadcast
        // u = 0: d1[t+base+l] * d2[t]
        a0 += w0.x * y.x; a1 += w0.y * y.x; a2 += w0.z * y.x; a3 += w0.w * y.x;
        // u = 1
        a0 += w0.y * y.y; a1 += w0.z * y.y; a2 += w0.w * y.y; a3 += w1.x * y.y;
        // u = 2
        a0 += w0.z * y.z; a1 += w0.w * y.z; a2 += w1.x * y.z; a3 += w1.y * y.z;
        // u = 3
        a0 += w0.w * y.w; a1 += w1.x * y.w; a2 += w1.y * y.w; a3 += w1.z * y.w;
        w0 = w1;
    }

    float* orow = out + (size_t)(chBase + c) * NOUT + base;
    if (base + 0 < NOUT) orow[0] = a0;
    if (base + 1 < NOUT) orow[1] = a1;
    if (base + 2 < NOUT) orow[2] = a2;
    if (base + 3 < NOUT) orow[3] = a3;
}

extern "C" void kernel_launch(void* const* d_in, const int* in_sizes, int n_in,
                              void* d_out, int out_size, void* d_ws, size_t ws_size,
                              hipStream_t stream) {
    const float* d1 = (const float*)d_in[0];
    const float* d2 = (const float*)d_in[1];
    float* out = (float*)d_out;
    const int nChannels = in_sizes[0] / NT;        // 64*32 = 2048
    const int grid = nChannels / CHPB;             // 1024 blocks
    xcorr_fp32_kernel<<<grid, BLOCK, 0, stream>>>(d1, d2, out);
}

// Round 2
// 26.180 us; speedup vs baseline: 12.6762x; 12.6762x over previous
//
#include <hip/hip_runtime.h>

// out[o] = sum_t d1[t + o - 301] * d2[t],  o in [0,603), t in [0,3000)
// Parity-split GEMM per channel:
//   o = 2*(16a + m) + par,  C_par[m,a] = sum_s d1[s + 2m + par - 301] * d2[s - 32a]
//   A_par[m,s] (Hankel, lane-shift 2 elems = 4B aligned), B[s,a] (16B-aligned b128)
// mfma_f32_16x16x32_bf16: A lane: m=l&15, k=8*(l>>4)+e ; B lane: n=l&15, same k
// C/D: lane l reg rr -> row m=4*(l>>4)+rr, col n=l&15   [guide §3, m89-verified]

#define NT    3000
#define NOUT  603
#define CHPB  4
#define BLOCK 256

// Per-channel LDS (bytes):
//   ld1: 6784 B (3392 bf16), ld1[i] = d1[i-304], data at elements [304,3304)
//   ld2: 8192 B (4096 bf16), ld2[i] = d2[i-768], data at elements [768,3768)
#define L1B  6784
#define L2B  8192
#define CHB  (L1B + L2B)      // 14976
#define TOTB (CHB * CHPB)     // 59904

typedef short bf16x8 __attribute__((ext_vector_type(8)));
typedef float f32x4  __attribute__((ext_vector_type(4)));

static __device__ __forceinline__ uint f2bf(float f) {
    union { float f; uint u; } a; a.f = f;            // RNE f32 -> bf16
    return (a.u + 0x7fffu + ((a.u >> 16) & 1u)) >> 16;
}

__global__ __launch_bounds__(BLOCK, 2) void xcorr_mfma(
    const float* __restrict__ d1g, const float* __restrict__ d2g,
    float* __restrict__ out)
{
    __shared__ __align__(16) unsigned char smem[TOTB];
    const int tid = threadIdx.x;

    // Zero all of LDS (pads must read as 0.0bf16).
    int4* z = (int4*)smem;
    for (int i = tid; i < TOTB / 16; i += BLOCK) z[i] = int4{0, 0, 0, 0};
    __syncthreads();

    const int chBase = blockIdx.x * CHPB;

    // Stage d1 -> bf16 at element offset 304 (byte 608, 8B-aligned uint2 writes).
    for (int i = tid; i < CHPB * 750; i += BLOCK) {
        const int c = i / 750, j = i % 750;
        const float4 v = *(const float4*)(d1g + (size_t)(chBase + c) * NT + 4 * j);
        uint2 p;
        p.x = f2bf(v.x) | (f2bf(v.y) << 16);
        p.y = f2bf(v.z) | (f2bf(v.w) << 16);
        *(uint2*)(smem + c * CHB + 608 + 8 * j) = p;
    }
    // Stage d2 -> bf16 at element offset 768 (byte 1536 within ld2).
    for (int i = tid; i < CHPB * 750; i += BLOCK) {
        const int c = i / 750, j = i % 750;
        const float4 v = *(const float4*)(d2g + (size_t)(chBase + c) * NT + 4 * j);
        uint2 p;
        p.x = f2bf(v.x) | (f2bf(v.y) << 16);
        p.y = f2bf(v.z) | (f2bf(v.w) << 16);
        *(uint2*)(smem + c * CHB + L1B + 1536 + 8 * j) = p;
    }
    __syncthreads();

    // One wave per channel.
    const int wid = tid >> 6, lane = tid & 63;
    const int q = lane >> 4, r = lane & 15;
    const uint* lA = (const uint*)(smem + wid * CHB);
    const uint* lB = (const uint*)(smem + wid * CHB + L1B);

    f32x4 a00 = {0.f,0.f,0.f,0.f};   // aPT: P = parity, T = n-tile
    f32x4 a10 = {0.f,0.f,0.f,0.f};
    f32x4 a01 = {0.f,0.f,0.f,0.f};
    f32x4 a11 = {0.f,0.f,0.f,0.f};

    // k-step s0 = 256 + 32*i, i in [0,96). A dword base = s0/2 + 4q + r + 2.
    int da = 128 + 4 * q + r + 2;
    // B dword base (tile0) = 384 + s0/2 + 4q - 16r ; tile1 = -256 dwords.
    int db = 384 + 128 + 4 * q - 16 * r;

    #pragma unroll 4
    for (int i = 0; i < 96; ++i) {
        const uint* pa = lA + da;
        const uint Dm1 = pa[-1], D0 = pa[0], D1 = pa[1], D2 = pa[2], D3 = pa[3];

        union { uint u[4]; bf16x8 v; int4 i4; } f1, f0, g0, g1;
        f1.u[0] = D0; f1.u[1] = D1; f1.u[2] = D2; f1.u[3] = D3;      // par=1 (odd o)
        f0.u[0] = (Dm1 >> 16) | (D0 << 16);                          // par=0 (even o)
        f0.u[1] = (D0  >> 16) | (D1 << 16);
        f0.u[2] = (D1  >> 16) | (D2 << 16);
        f0.u[3] = (D2  >> 16) | (D3 << 16);
        g0.i4 = *(const int4*)(lB + db);          // n-tile a in [0,16)
        g1.i4 = *(const int4*)(lB + db - 256);    // n-tile a in [16,32)

        a00 = __builtin_amdgcn_mfma_f32_16x16x32_bf16(f0.v, g0.v, a00, 0, 0, 0);
        a10 = __builtin_amdgcn_mfma_f32_16x16x32_bf16(f1.v, g0.v, a10, 0, 0, 0);
        a01 = __builtin_amdgcn_mfma_f32_16x16x32_bf16(f0.v, g1.v, a01, 0, 0, 0);
        a11 = __builtin_amdgcn_mfma_f32_16x16x32_bf16(f1.v, g1.v, a11, 0, 0, 0);

        da += 16; db += 16;
    }

    // Store: lane (q,r), reg rr, parity p -> o = 512*tile + 32r + 8q + 2rr + p.
    float* o = out + (size_t)(chBase + wid) * NOUT;
    {
        const int X = 32 * r + 8 * q;             // tile0: X+7 <= 511 < 603 always
        float4 s0 = {a00[0], a10[0], a00[1], a10[1]};
        float4 s1 = {a00[2], a10[2], a00[3], a10[3]};
        *(float4*)(o + X)     = s0;
        *(float4*)(o + X + 4) = s1;
    }
    {
        const int X = 512 + 32 * r + 8 * q;
        if (X + 7 < NOUT) {
            float4 s0 = {a01[0], a11[0], a01[1], a11[1]};
            float4 s1 = {a01[2], a11[2], a01[3], a11[3]};
            *(float4*)(o + X)     = s0;
            *(float4*)(o + X + 4) = s1;
        } else if (X < NOUT) {
            const float v[8] = {a01[0], a11[0], a01[1], a11[1],
                                a01[2], a11[2], a01[3], a11[3]};
            #pragma unroll
            for (int e = 0; e < 8; ++e)
                if (X + e < NOUT) o[X + e] = v[e];
        }
    }
}

extern "C" void kernel_launch(void* const* d_in, const int* in_sizes, int n_in,
                              void* d_out, int out_size, void* d_ws, size_t ws_size,
                              hipStream_t stream) {
    const float* d1 = (const float*)d_in[0];
    const float* d2 = (const float*)d_in[1];
    float* out = (float*)d_out;
    const int nChannels = in_sizes[0] / NT;     // 2048
    const int grid = nChannels / CHPB;          // 512
    xcorr_mfma<<<grid, BLOCK, 0, stream>>>(d1, d2, out);
}

// Round 3
// 25.692 us; speedup vs baseline: 12.9169x; 1.0190x over previous
//
#include <hip/hip_runtime.h>

// out[o] = sum_t d1[t + o - 301] * d2[t],  o in [0,603), t in [0,3000)
// Parity-split GEMM per channel:
//   o = 2*(16a + m) + par,  C_par[m,a] = sum_s d1[s + 2m + par - 301] * d2[s - 32a]
// mfma_f32_16x16x32_bf16; C/D: lane l reg rr -> row m=4*(l>>4)+rr, col n=l&15.
// B-fragment FIFO: tile1 frag at step i == tile0 frag at step i-16, kept in a
// 16-deep statically-indexed register FIFO -> one ds_read_b128 per k-step.

#define NT    3000
#define NOUT  603
#define CHPB  4
#define BLOCK 256

// Per-channel LDS (bytes):
//   ld1: 6784 B (3392 bf16), ld1[i] = d1[i-304], data elems [304,3304)
//   ld2: 8192 B (4096 bf16), ld2[i] = d2[i-768], data elems [768,3768)
#define L1B  6784
#define L2B  8192
#define CHB  (L1B + L2B)      // 14976
#define TOTB (CHB * CHPB)     // 59904

typedef short bf16x8 __attribute__((ext_vector_type(8)));
typedef float f32x4  __attribute__((ext_vector_type(4)));

static __device__ __forceinline__ uint f2bf(float f) {
    union { float f; uint u; } a; a.f = f;            // RNE f32 -> bf16
    return (a.u + 0x7fffu + ((a.u >> 16) & 1u)) >> 16;
}

__global__ __launch_bounds__(BLOCK, 2) void xcorr_mfma(
    const float* __restrict__ d1g, const float* __restrict__ d2g,
    float* __restrict__ out)
{
    __shared__ __align__(16) unsigned char smem[TOTB];
    const int tid = threadIdx.x;
    const int chBase = blockIdx.x * CHPB;

    // --- Zero ONLY the pad regions (disjoint from staged data; one barrier).
    // d1 pads: dwords [0,152) u [1652,1696)   (196 dwords/ch)
    // d2 pads: dwords [0,384) u [1884,2048)   (548 dwords/ch)
    for (int i = tid; i < CHPB * 196; i += BLOCK) {
        const int c = i / 196, j = i % 196;
        const int dw = (j < 152) ? j : (1652 + (j - 152));
        ((uint*)(smem + c * CHB))[dw] = 0u;
    }
    for (int i = tid; i < CHPB * 548; i += BLOCK) {
        const int c = i / 548, j = i % 548;
        const int dw = (j < 384) ? j : (1884 + (j - 384));
        ((uint*)(smem + c * CHB + L1B))[dw] = 0u;
    }

    // --- Stage d1 -> bf16 at element 304 (byte 608); d2 at element 768.
    for (int i = tid; i < CHPB * 750; i += BLOCK) {
        const int c = i / 750, j = i % 750;
        const float4 v = *(const float4*)(d1g + (size_t)(chBase + c) * NT + 4 * j);
        uint2 p;
        p.x = f2bf(v.x) | (f2bf(v.y) << 16);
        p.y = f2bf(v.z) | (f2bf(v.w) << 16);
        *(uint2*)(smem + c * CHB + 608 + 8 * j) = p;
    }
    for (int i = tid; i < CHPB * 750; i += BLOCK) {
        const int c = i / 750, j = i % 750;
        const float4 v = *(const float4*)(d2g + (size_t)(chBase + c) * NT + 4 * j);
        uint2 p;
        p.x = f2bf(v.x) | (f2bf(v.y) << 16);
        p.y = f2bf(v.z) | (f2bf(v.w) << 16);
        *(uint2*)(smem + c * CHB + L1B + 1536 + 8 * j) = p;
    }
    __syncthreads();

    // --- One wave per channel.
    const int wid = tid >> 6, lane = tid & 63;
    const int q = lane >> 4, r = lane & 15;
    const uint* lA = (const uint*)(smem + wid * CHB);
    const uint* lB = (const uint*)(smem + wid * CHB + L1B);

    f32x4 a00 = {0.f,0.f,0.f,0.f};   // aPT: P = parity, T = n-tile
    f32x4 a10 = {0.f,0.f,0.f,0.f};
    f32x4 a01 = {0.f,0.f,0.f,0.f};
    f32x4 a11 = {0.f,0.f,0.f,0.f};

    // B FIFO prefill: slot s <- tile0 frag of step s-16 (dwords 256+4q-16r+16s).
    int4 fifo[16];
    {
        const int dbP = 256 + 4 * q - 16 * r;
        #pragma unroll
        for (int s = 0; s < 16; ++s)
            fifo[s] = *(const int4*)(lB + dbP + 16 * s);
    }

    int da = 130 + 4 * q + r;            // A dword base at step i (+16/step)
    int db = 512 + 4 * q - 16 * r;       // tile0 B dword base at step i

    for (int jo = 0; jo < 6; ++jo) {
        #pragma unroll
        for (int u = 0; u < 16; ++u) {
            const uint* pa = lA + da;
            const uint Dm1 = pa[-1], D0 = pa[0], D1 = pa[1], D2 = pa[2], D3 = pa[3];

            union { uint w[4]; bf16x8 v; int4 i4; } f1, f0, g0, g1;
            f1.w[0] = D0; f1.w[1] = D1; f1.w[2] = D2; f1.w[3] = D3;   // par=1
            f0.w[0] = (Dm1 >> 16) | (D0 << 16);                       // par=0
            f0.w[1] = (D0  >> 16) | (D1 << 16);
            f0.w[2] = (D1  >> 16) | (D2 << 16);
            f0.w[3] = (D2  >> 16) | (D3 << 16);

            g0.i4 = *(const int4*)(lB + db);   // tile0 frag (step i)
            g1.i4 = fifo[u];                   // tile1 frag (= tile0 @ i-16)
            fifo[u] = g0.i4;

            a00 = __builtin_amdgcn_mfma_f32_16x16x32_bf16(f0.v, g0.v, a00, 0, 0, 0);
            a10 = __builtin_amdgcn_mfma_f32_16x16x32_bf16(f1.v, g0.v, a10, 0, 0, 0);
            a01 = __builtin_amdgcn_mfma_f32_16x16x32_bf16(f0.v, g1.v, a01, 0, 0, 0);
            a11 = __builtin_amdgcn_mfma_f32_16x16x32_bf16(f1.v, g1.v, a11, 0, 0, 0);

            da += 16; db += 16;
        }
    }

    // Store: lane (q,r), reg rr, parity p -> o = 512*tile + 32r + 8q + 2rr + p.
    float* o = out + (size_t)(chBase + wid) * NOUT;
    {
        const int X = 32 * r + 8 * q;            // tile0: X+7 <= 511 < 603
        float4 s0 = {a00[0], a10[0], a00[1], a10[1]};
        float4 s1 = {a00[2], a10[2], a00[3], a10[3]};
        *(float4*)(o + X)     = s0;
        *(float4*)(o + X + 4) = s1;
    }
    {
        const int X = 512 + 32 * r + 8 * q;
        if (X + 7 < NOUT) {
            float4 s0 = {a01[0], a11[0], a01[1], a11[1]};
            float4 s1 = {a01[2], a11[2], a01[3], a11[3]};
            *(float4*)(o + X)     = s0;
            *(float4*)(o + X + 4) = s1;
        } else if (X < NOUT) {
            const float v[8] = {a01[0], a11[0], a01[1], a11[1],
                                a01[2], a11[2], a01[3], a11[3]};
            #pragma unroll
            for (int e = 0; e < 8; ++e)
                if (X + e < NOUT) o[X + e] = v[e];
        }
    }
}

extern "C" void kernel_launch(void* const* d_in, const int* in_sizes, int n_in,
                              void* d_out, int out_size, void* d_ws, size_t ws_size,
                              hipStream_t stream) {
    const float* d1 = (const float*)d_in[0];
    const float* d2 = (const float*)d_in[1];
    float* out = (float*)d_out;
    const int nChannels = in_sizes[0] / NT;     // 2048
    const int grid = nChannels / CHPB;          // 512
    xcorr_mfma<<<grid, BLOCK, 0, stream>>>(d1, d2, out);
}

// Round 4
// 21.779 us; speedup vs baseline: 15.2376x; 1.1797x over previous
//
#include <hip/hip_runtime.h>

// out[o] = sum_t d1[t + o - 301] * d2[t],  o in [0,603), t in [0,3000)
// Parity-split GEMM per channel (indexing identical to round-3 kernel):
//   o = 2*(16a + m) + par,  C_par[m,a] = sum_s d1[s + 2m + par - 301] * d2[s - 32a]
// One wave per channel (BLOCK=64, grid=2048): staging is STREAMED through the
// k-loop in 6 chunks of 16 k-steps; per chunk, 4 guarded float4 global loads
// are issued before the MFMA steps and converted/ds_write_b128'd after.
// No __syncthreads anywhere. B-fragment FIFO as in round 3.
//
// LDS (dwords): l1[1696]: ld1[e]=d1[e-304] elems, data dwords [152,1652),
//               pads zeroed [0,152)+[1652,1696); reads touch [129,1681).
//               l2[2048]: ld2[e]=d2[e-768], data dwords [384,1884),
//               pads zeroed [0,384)+[1884,2048); reads touch [16,2048).

#define NT    3000
#define NOUT  603
#define BLOCK 64
#define L1DW  1696
#define L2DW  2048

typedef short bf16x8 __attribute__((ext_vector_type(8)));
typedef float f32x4  __attribute__((ext_vector_type(4)));

static __device__ __forceinline__ uint f2bf(float f) {
    union { float f; uint u; } a; a.f = f;            // RNE f32 -> bf16
    return (a.u + 0x7fffu + ((a.u >> 16) & 1u)) >> 16;
}

__global__ __launch_bounds__(BLOCK, 2) void xcorr_mfma(
    const float* __restrict__ d1g, const float* __restrict__ d2g,
    float* __restrict__ out)
{
    __shared__ __align__(16) uint l1[L1DW];
    __shared__ __align__(16) uint l2[L2DW];

    const int lane = threadIdx.x & 63;
    const int q = lane >> 4, r = lane & 15;
    const int ch = blockIdx.x;
    const float* __restrict__ g1 = d1g + (size_t)ch * NT;
    const float* __restrict__ g2 = d2g + (size_t)ch * NT;

    // --- Zero pad regions (disjoint from data; same-wave ordering is program
    // order through LDS, compiler inserts lgkmcnt waits).
    for (int j = lane; j < 196; j += BLOCK) {
        const int dw = (j < 152) ? j : 1652 + (j - 152);
        l1[dw] = 0u;
    }
    for (int j = lane; j < 548; j += BLOCK) {
        const int dw = (j < 384) ? j : 1884 + (j - 384);
        l2[dw] = 0u;
    }

    // --- 256-dword staging primitive: lane handles dwords [dstart+4*lane, +4).
    auto stageA = [&](int dstart) {
        const int d = dstart + 4 * lane;
        const int e0 = 2 * (d - 152);               // d1 element index
        if (e0 < NT) {                              // data region ends at 3000
            const float4 v = *(const float4*)(g1 + e0);
            const float4 w = *(const float4*)(g1 + e0 + 4);
            int4 p;
            p.x = (int)(f2bf(v.x) | (f2bf(v.y) << 16));
            p.y = (int)(f2bf(v.z) | (f2bf(v.w) << 16));
            p.z = (int)(f2bf(w.x) | (f2bf(w.y) << 16));
            p.w = (int)(f2bf(w.z) | (f2bf(w.w) << 16));
            *(int4*)(l1 + d) = p;
        }
    };
    auto stageB = [&](int dstart) {
        const int d = dstart + 4 * lane;
        const int e0 = 2 * (d - 384);               // d2 element index
        if (e0 < NT) {
            const float4 v = *(const float4*)(g2 + e0);
            const float4 w = *(const float4*)(g2 + e0 + 4);
            int4 p;
            p.x = (int)(f2bf(v.x) | (f2bf(v.y) << 16));
            p.y = (int)(f2bf(v.z) | (f2bf(v.w) << 16));
            p.z = (int)(f2bf(w.x) | (f2bf(w.y) << 16));
            p.w = (int)(f2bf(w.z) | (f2bf(w.w) << 16));
            *(int4*)(l2 + d) = p;
        }
    };

    // --- Prologue: A dwords [152,664), B dwords [384,896).
    stageA(152); stageA(408);
    stageB(384); stageB(640);

    // --- B FIFO prefill: slot s <- tile0 frag of step s-16 (reads [16,512)).
    int4 fifo[16];
    {
        const int dbP = 256 + 4 * q - 16 * r;
        #pragma unroll
        for (int s = 0; s < 16; ++s)
            fifo[s] = *(const int4*)(l2 + dbP + 16 * s);
    }

    f32x4 a00 = {0.f,0.f,0.f,0.f};   // aPT: P = parity, T = n-tile
    f32x4 a10 = {0.f,0.f,0.f,0.f};
    f32x4 a01 = {0.f,0.f,0.f,0.f};
    f32x4 a11 = {0.f,0.f,0.f,0.f};

    int da = 130 + 4 * q + r;        // A dword base (+16/step)
    int db = 512 + 4 * q - 16 * r;   // tile0 B dword base (+16/step)
    int aPre = 664, bPre = 896;      // staged frontiers

    for (int c = 0; c < 6; ++c) {
        // Prefetch loads for future chunks (issued before the MFMA steps).
        const int dA = aPre + 4 * lane, eA = 2 * (dA - 152);
        const int dB = bPre + 4 * lane, eB = 2 * (dB - 384);
        const bool okA = eA < NT, okB = eB < NT;
        float4 va0, va1, vb0, vb1;
        if (okA) { va0 = *(const float4*)(g1 + eA); va1 = *(const float4*)(g1 + eA + 4); }
        if (okB) { vb0 = *(const float4*)(g2 + eB); vb1 = *(const float4*)(g2 + eB + 4); }

        #pragma unroll
        for (int u = 0; u < 16; ++u) {
            const uint* pa = (const uint*)l1 + da;
            const uint Dm1 = pa[-1], D0 = pa[0], D1 = pa[1], D2 = pa[2], D3 = pa[3];

            union { uint w[4]; bf16x8 v; int4 i4; } f1, f0, g0, g1u;
            f1.w[0] = D0; f1.w[1] = D1; f1.w[2] = D2; f1.w[3] = D3;   // par=1
            f0.w[0] = (Dm1 >> 16) | (D0 << 16);                       // par=0
            f0.w[1] = (D0  >> 16) | (D1 << 16);
            f0.w[2] = (D1  >> 16) | (D2 << 16);
            f0.w[3] = (D2  >> 16) | (D3 << 16);

            g0.i4 = *(const int4*)((const uint*)l2 + db);  // tile0 (step i)
            g1u.i4 = fifo[u];                              // tile1 (= tile0 @ i-16)
            fifo[u] = g0.i4;

            a00 = __builtin_amdgcn_mfma_f32_16x16x32_bf16(f0.v, g0.v,  a00, 0, 0, 0);
            a10 = __builtin_amdgcn_mfma_f32_16x16x32_bf16(f1.v, g0.v,  a10, 0, 0, 0);
            a01 = __builtin_amdgcn_mfma_f32_16x16x32_bf16(f0.v, g1u.v, a01, 0, 0, 0);
            a11 = __builtin_amdgcn_mfma_f32_16x16x32_bf16(f1.v, g1u.v, a11, 0, 0, 0);

            da += 16; db += 16;
        }

        // Convert + LDS write (read by chunk c+1/c+2 -> a chunk of slack).
        if (okA) {
            int4 p;
            p.x = (int)(f2bf(va0.x) | (f2bf(va0.y) << 16));
            p.y = (int)(f2bf(va0.z) | (f2bf(va0.w) << 16));
            p.z = (int)(f2bf(va1.x) | (f2bf(va1.y) << 16));
            p.w = (int)(f2bf(va1.z) | (f2bf(va1.w) << 16));
            *(int4*)(l1 + dA) = p;
        }
        if (okB) {
            int4 p;
            p.x = (int)(f2bf(vb0.x) | (f2bf(vb0.y) << 16));
            p.y = (int)(f2bf(vb0.z) | (f2bf(vb0.w) << 16));
            p.z = (int)(f2bf(vb1.x) | (f2bf(vb1.y) << 16));
            p.w = (int)(f2bf(vb1.z) | (f2bf(vb1.w) << 16));
            *(int4*)(l2 + dB) = p;
        }
        aPre += 256; bPre += 256;
    }

    // --- Store: lane (q,r), reg rr, parity p -> o = 512*tile + 32r + 8q + 2rr + p.
    float* o = out + (size_t)ch * NOUT;
    {
        const int X = 32 * r + 8 * q;            // tile0: X+7 <= 511 < 603
        float4 s0 = {a00[0], a10[0], a00[1], a10[1]};
        float4 s1 = {a00[2], a10[2], a00[3], a10[3]};
        *(float4*)(o + X)     = s0;
        *(float4*)(o + X + 4) = s1;
    }
    {
        const int X = 512 + 32 * r + 8 * q;
        if (X + 7 < NOUT) {
            float4 s0 = {a01[0], a11[0], a01[1], a11[1]};
            float4 s1 = {a01[2], a11[2], a01[3], a11[3]};
            *(float4*)(o + X)     = s0;
            *(float4*)(o + X + 4) = s1;
        } else if (X < NOUT) {
            const float v[8] = {a01[0], a11[0], a01[1], a11[1],
                                a01[2], a11[2], a01[3], a11[3]};
            #pragma unroll
            for (int e = 0; e < 8; ++e)
                if (X + e < NOUT) o[X + e] = v[e];
        }
    }
}

extern "C" void kernel_launch(void* const* d_in, const int* in_sizes, int n_in,
                              void* d_out, int out_size, void* d_ws, size_t ws_size,
                              hipStream_t stream) {
    const float* d1 = (const float*)d_in[0];
    const float* d2 = (const float*)d_in[1];
    float* out = (float*)d_out;
    const int nChannels = in_sizes[0] / NT;     // 2048
    xcorr_mfma<<<nChannels, BLOCK, 0, stream>>>(d1, d2, out);
}